// Round 1
// baseline (7609.863 us; speedup 1.0000x reference)
//
#include <hip/hip_runtime.h>
#include <math.h>

#define FS_   44100.0
#define B_    8
#define T_    22050
#define NCH   31
#define LG    2048
#define LH    512
#define MM    12
#define BN    248          // B_*NCH

#define H1LEN 1023         // LH+LH-1

#define C2T   512          // t-tile for conv2/ihc
#define C2THR 128          // threads (each does 4 consecutive t)

#define IHCK  128          // IHC FIR taps

#define MODL  441
#define MODC  50           // MODL*MODC == T_

// ---- workspace layout (in floats) ----
#define OFF_H1    0                      // 1024
#define OFF_G5    1024                   // 256
#define OFF_X1    1280                   // 176512 (B_*T_=176400)
#define OFF_HW    (OFF_X1 + 176512)      // 5468416 (BN*T_=5468400)
#define OFF_ENV   (OFF_HW + 5468416)     // 5468416
#define OFF_AD    OFF_HW                 // alias: hw dead after IHC
#define OFF_SEND  (OFF_ENV + 5468416)    // 297600 floats (float2 x 148800)
#define OFF_SINIT (OFF_SEND + 297600)    // 297600
// total = 11,709,824 floats = 46.9 MB

struct ScanP {
  float a1[5], b0[5], factor[5], efl2[5], offset[5], init[5], rinit[5];
  float minlvl, corr, scale;
};
struct ModP {
  float pre[12], pim[12], pb0[12], pLre[12], pLim[12];
  float att;
};

// ---------- combined hp*me FIR (length 1023) ----------
__global__ void k_h1(const float* __restrict__ hp, const float* __restrict__ me,
                     float* __restrict__ h1) {
  int k = blockIdx.x * blockDim.x + threadIdx.x;
  if (k >= H1LEN) return;
  int j0 = max(0, k - (LH - 1));
  int j1 = min(LH - 1, k);
  float acc = 0.f;
  for (int j = j0; j <= j1; ++j) acc += hp[j] * me[k - j];
  h1[k] = acc;
}

// ---------- IHC LP^5 impulse response: (1-a)^5 * C(k+4,4) * a^k ----------
__global__ void k_g5(float l2a, float c5, float* __restrict__ g5) {
  int k = threadIdx.x;  // 128
  float kf = (float)k;
  float binom = (kf + 1.f) * (kf + 2.f) * (kf + 3.f) * (kf + 4.f) * (1.0f / 24.0f);
  g5[k] = c5 * binom * exp2f(kf * l2a);
}

// ---------- conv1: x (*) h1 -> x1,  K=1023, 1 output/thread ----------
__global__ void k_conv1(const float* __restrict__ x, const float* __restrict__ h1,
                        float* __restrict__ x1) {
  __shared__ float xs[256 + 1022];  // 1278
  __shared__ float hs[H1LEN];
  int b = blockIdx.y;
  int t0 = blockIdx.x * 256;
  const float* xb = x + b * T_;
  for (int i = threadIdx.x; i < 1278; i += 256) {
    int g = t0 - 1022 + i;
    xs[i] = (g >= 0 && g < T_) ? xb[g] : 0.f;
  }
  for (int i = threadIdx.x; i < H1LEN; i += 256) hs[i] = h1[i];
  __syncthreads();
  int t = t0 + threadIdx.x;
  if (t >= T_) return;
  float acc = 0.f;
  for (int k = 0; k < H1LEN; ++k) acc = fmaf(hs[k], xs[threadIdx.x + 1022 - k], acc);
  x1[b * T_ + t] = acc;
}

// ---------- conv2: x1 (*) gt[n] -> hw = relu(y), K=2048, 4 outputs/thread ----------
__global__ __launch_bounds__(C2THR) void k_conv2(const float* __restrict__ x1,
                                                 const float* __restrict__ gt,
                                                 float* __restrict__ hw) {
  const int H = LG - 1;  // 2047
  __shared__ __align__(16) float xs[C2T + LG];  // 2560
  __shared__ __align__(16) float hs[LG];
  int n = blockIdx.y % NCH, b = blockIdx.y / NCH;
  int t0 = blockIdx.x * C2T;
  const float* xb = x1 + b * T_;
  for (int i = threadIdx.x; i < C2T + LG; i += C2THR) {
    int g = t0 - H + i;
    xs[i] = (g >= 0 && g < T_) ? xb[g] : 0.f;
  }
  for (int i = threadIdx.x; i < LG; i += C2THR) hs[i] = gt[n * LG + i];
  __syncthreads();
  int base = threadIdx.x * 4;
  float a0 = 0.f, a1 = 0.f, a2 = 0.f, a3 = 0.f;
  float4 hi = *(const float4*)&xs[base + H + 1];  // [base+H+1 .. base+H+4]
  for (int k4 = 0; k4 < LG / 4; ++k4) {
    int k = k4 * 4;
    float4 lo = *(const float4*)&xs[base + H - 3 - k];  // [base+H-3-k .. base+H-k]
    float4 hh = *(const float4*)&hs[k];
    a0 = fmaf(hh.x, lo.w, a0); a1 = fmaf(hh.x, hi.x, a1); a2 = fmaf(hh.x, hi.y, a2); a3 = fmaf(hh.x, hi.z, a3);
    a0 = fmaf(hh.y, lo.z, a0); a1 = fmaf(hh.y, lo.w, a1); a2 = fmaf(hh.y, hi.x, a2); a3 = fmaf(hh.y, hi.y, a3);
    a0 = fmaf(hh.z, lo.y, a0); a1 = fmaf(hh.z, lo.z, a1); a2 = fmaf(hh.z, lo.w, a2); a3 = fmaf(hh.z, hi.x, a3);
    a0 = fmaf(hh.w, lo.x, a0); a1 = fmaf(hh.w, lo.y, a1); a2 = fmaf(hh.w, lo.z, a2); a3 = fmaf(hh.w, lo.w, a3);
    hi = lo;
  }
  float* o = hw + (size_t)(b * NCH + n) * T_;
  int t = t0 + base;
  if (t + 0 < T_) o[t + 0] = fmaxf(a0, 0.f);
  if (t + 1 < T_) o[t + 1] = fmaxf(a1, 0.f);
  if (t + 2 < T_) o[t + 2] = fmaxf(a2, 0.f);
  if (t + 3 < T_) o[t + 3] = fmaxf(a3, 0.f);
}

// ---------- IHC FIR: hw (*) g5 -> env, K=128, 4 outputs/thread ----------
__global__ __launch_bounds__(C2THR) void k_ihc(const float* __restrict__ hw,
                                               const float* __restrict__ g5,
                                               float* __restrict__ env) {
  const int H = IHCK - 1;  // 127
  __shared__ __align__(16) float xs[C2T + IHCK];  // 640
  __shared__ __align__(16) float hs[IHCK];
  int bn = blockIdx.y;
  int t0 = blockIdx.x * C2T;
  const float* xb = hw + (size_t)bn * T_;
  for (int i = threadIdx.x; i < C2T + IHCK; i += C2THR) {
    int g = t0 - H + i;
    xs[i] = (g >= 0 && g < T_) ? xb[g] : 0.f;
  }
  if (threadIdx.x < IHCK) hs[threadIdx.x] = g5[threadIdx.x];
  __syncthreads();
  int base = threadIdx.x * 4;
  float a0 = 0.f, a1 = 0.f, a2 = 0.f, a3 = 0.f;
  float4 hi = *(const float4*)&xs[base + H + 1];
  for (int k4 = 0; k4 < IHCK / 4; ++k4) {
    int k = k4 * 4;
    float4 lo = *(const float4*)&xs[base + H - 3 - k];
    float4 hh = *(const float4*)&hs[k];
    a0 = fmaf(hh.x, lo.w, a0); a1 = fmaf(hh.x, hi.x, a1); a2 = fmaf(hh.x, hi.y, a2); a3 = fmaf(hh.x, hi.z, a3);
    a0 = fmaf(hh.y, lo.z, a0); a1 = fmaf(hh.y, lo.w, a1); a2 = fmaf(hh.y, hi.x, a2); a3 = fmaf(hh.y, hi.y, a3);
    a0 = fmaf(hh.z, lo.y, a0); a1 = fmaf(hh.z, lo.z, a1); a2 = fmaf(hh.z, lo.w, a2); a3 = fmaf(hh.z, hi.x, a3);
    a0 = fmaf(hh.w, lo.x, a0); a1 = fmaf(hh.w, lo.y, a1); a2 = fmaf(hh.w, lo.z, a2); a3 = fmaf(hh.w, lo.w, a3);
    hi = lo;
  }
  float* o = env + (size_t)bn * T_;
  int t = t0 + base;
  if (t + 0 < T_) o[t + 0] = a0;
  if (t + 1 < T_) o[t + 1] = a1;
  if (t + 2 < T_) o[t + 2] = a2;
  if (t + 3 < T_) o[t + 3] = a3;
}

// ---------- adaptation loops: sequential scan over T per (b,n) ----------
__global__ __launch_bounds__(64) void k_scan(const float* __restrict__ env,
                                             float* __restrict__ ad, ScanP p) {
  int seq = blockIdx.x * 64 + threadIdx.x;
  if (seq >= BN) return;
  const float* e = env + (size_t)seq * T_;
  float* o = ad + (size_t)seq * T_;
  float st[5], r[5];
#pragma unroll
  for (int j = 0; j < 5; ++j) { st[j] = p.init[j]; r[j] = p.rinit[j]; }
  float ecur = e[0];
  for (int t = 0; t < T_; ++t) {
    float enext = e[t + 1];  // 1-elem overread lands in ws padding; value dead at t=T_-1
    float tmp = fmaxf(ecur, p.minlvl);
#pragma unroll
    for (int j = 0; j < 5; ++j) {
      tmp = tmp * r[j];  // tmp / state[j], rcp hoisted off critical path
      float ex = __builtin_amdgcn_exp2f(p.efl2[j] * (tmp - 1.0f));
      float lim = fmaf(p.factor[j], __builtin_amdgcn_rcpf(1.0f + ex), -p.offset[j]);
      tmp = (tmp > 1.0f) ? lim : tmp;
      st[j] = fmaf(p.a1[j], st[j], p.b0[j] * tmp);
      r[j] = __builtin_amdgcn_rcpf(st[j]);  // for next step; not on this step's chain
    }
    o[t] = (tmp - p.corr) * p.scale;
    ecur = enext;
  }
}

// ---------- modulation filterbank, chunk-parallel linear scan ----------
__global__ void k_modA(const float* __restrict__ ad, float2* __restrict__ send, ModP mp) {
  int id = blockIdx.x * 256 + threadIdx.x;
  if (id >= MODC * BN * MM) return;
  int m = id % MM, bn = (id / MM) % BN, c = id / (MM * BN);
  const float* a = ad + (size_t)bn * T_ + c * MODL;
  float pre = mp.pre[m], pim = mp.pim[m], b0 = mp.pb0[m];
  float sre = 0.f, sim = 0.f;
  for (int i = 0; i < MODL; ++i) {
    float xv = a[i];
    float nre = fmaf(pre, sre, fmaf(-pim, sim, b0 * xv));
    sim = fmaf(pre, sim, pim * sre);
    sre = nre;
  }
  send[id] = make_float2(sre, sim);
}

__global__ void k_modB(const float2* __restrict__ send, float2* __restrict__ sinit, ModP mp) {
  int id = blockIdx.x * blockDim.x + threadIdx.x;
  if (id >= BN * MM) return;
  int m = id % MM;
  float pLre = mp.pLre[m], pLim = mp.pLim[m];
  float Sre = 0.f, Sim = 0.f;
  for (int c = 0; c < MODC; ++c) {
    int idx = c * BN * MM + id;
    sinit[idx] = make_float2(Sre, Sim);
    float2 se = send[idx];
    float nre = pLre * Sre - pLim * Sim + se.x;
    Sim = pLre * Sim + pLim * Sre + se.y;
    Sre = nre;
  }
}

__global__ void k_modC(const float* __restrict__ ad, const float2* __restrict__ sinit,
                       float* __restrict__ out, ModP mp) {
  int id = blockIdx.x * 256 + threadIdx.x;
  if (id >= MODC * BN * MM) return;
  int m = id % MM, bn = (id / MM) % BN, c = id / (MM * BN);
  const float* a = ad + (size_t)bn * T_ + c * MODL;
  float* o = out + ((size_t)bn * MM + m) * T_ + c * MODL;
  float2 s0 = sinit[id];
  float sre = s0.x, sim = s0.y;
  float pre = mp.pre[m], pim = mp.pim[m], b0 = mp.pb0[m], att = mp.att;
  bool low = (m < 3);  // mfc <= 10 Hz
  for (int i = 0; i < MODL; ++i) {
    float xv = a[i];
    float nre = fmaf(pre, sre, fmaf(-pim, sim, b0 * xv));
    sim = fmaf(pre, sim, pim * sre);
    sre = nre;
    float mag = att * sqrtf(fmaf(sre, sre, fmaf(sim, sim, 1e-12f)));
    o[i] = low ? sre : mag;
  }
}

extern "C" void kernel_launch(void* const* d_in, const int* in_sizes, int n_in,
                              void* d_out, int out_size, void* d_ws, size_t ws_size,
                              hipStream_t stream) {
  const float* x  = (const float*)d_in[0];
  const float* hp = (const float*)d_in[1];
  const float* me = (const float*)d_in[2];
  const float* gt = (const float*)d_in[3];
  float* ws  = (float*)d_ws;
  float* out = (float*)d_out;

  // ---- host-side constant computation (double precision) ----
  ScanP sp;
  const double taus[5] = {0.005, 0.05, 0.129, 0.253, 0.5};
  for (int j = 0; j < 5; ++j) {
    double a1 = exp(-1.0 / (FS_ * taus[j]));
    double init = pow(1e-5, pow(2.0, -(double)(j + 1)));
    double maxv = (1.0 - init * init) * 5.0 - 1.0;
    sp.a1[j] = (float)a1;
    sp.b0[j] = (float)(1.0 - a1);
    sp.factor[j] = (float)(2.0 * maxv);
    sp.efl2[j] = (float)(-2.0 / maxv * 1.4426950408889634);  // expfac * log2(e)
    sp.offset[j] = (float)(maxv - 1.0);
    sp.init[j] = (float)init;
    sp.rinit[j] = (float)(1.0 / init);
  }
  sp.minlvl = 1e-5f;
  double corr = pow(1e-5, pow(2.0, -5.0));
  sp.corr = (float)corr;
  sp.scale = (float)(100.0 / (1.0 - corr));

  ModP mp;
  const double mfc[12] = {2.5, 5.0, 10.0, 16.7, 27.8, 46.3, 77.2, 128.6, 214.3, 357.2, 595.4, 992.3};
  for (int m = 0; m < 12; ++m) {
    double r = exp(-M_PI * (mfc[m] / 2.0) / FS_);
    double th = 2.0 * M_PI * mfc[m] / FS_;
    mp.pre[m] = (float)(r * cos(th));
    mp.pim[m] = (float)(r * sin(th));
    mp.pb0[m] = (float)(1.0 - r);
    double rL = pow(r, (double)MODL);
    mp.pLre[m] = (float)(rL * cos((double)MODL * th));
    mp.pLim[m] = (float)(rL * sin((double)MODL * th));
  }
  mp.att = (float)(1.0 / sqrt(2.0));

  double alp = exp(-2.0 * M_PI * 2000.0 / FS_);
  float l2a = (float)(log(alp) * 1.4426950408889634);
  float c5  = (float)pow(1.0 - alp, 5.0);

  float* h1  = ws + OFF_H1;
  float* g5  = ws + OFF_G5;
  float* x1  = ws + OFF_X1;
  float* hw  = ws + OFF_HW;
  float* env = ws + OFF_ENV;
  float* ad  = ws + OFF_AD;  // aliases hw (dead after IHC)
  float2* send  = (float2*)(ws + OFF_SEND);
  float2* sinit = (float2*)(ws + OFF_SINIT);

  k_h1<<<dim3(2), dim3(512), 0, stream>>>(hp, me, h1);
  k_g5<<<dim3(1), dim3(128), 0, stream>>>(l2a, c5, g5);
  k_conv1<<<dim3(87, B_), dim3(256), 0, stream>>>(x, h1, x1);
  k_conv2<<<dim3((T_ + C2T - 1) / C2T, BN), dim3(C2THR), 0, stream>>>(x1, gt, hw);
  k_ihc<<<dim3((T_ + C2T - 1) / C2T, BN), dim3(C2THR), 0, stream>>>(hw, g5, env);
  k_scan<<<dim3(4), dim3(64), 0, stream>>>(env, ad, sp);
  int nmod = MODC * BN * MM;
  k_modA<<<dim3((nmod + 255) / 256), dim3(256), 0, stream>>>(ad, send, mp);
  k_modB<<<dim3((BN * MM + 255) / 256), dim3(256), 0, stream>>>(send, sinit, mp);
  k_modC<<<dim3((nmod + 255) / 256), dim3(256), 0, stream>>>(ad, sinit, out, mp);
}

// Round 2
// 3020.954 us; speedup vs baseline: 2.5190x; 2.5190x over previous
//
#include <hip/hip_runtime.h>
#include <math.h>

#define FS_   44100.0
#define B_    8
#define T_    22050
#define NCH   31
#define LG    2048
#define LH    512
#define MM    12
#define BN    248          // B_*NCH

#define H1LEN 1023         // LH+LH-1

#define C2T   512          // t-tile for conv2/ihc
#define C2THR 128          // threads (each does 4 consecutive t)

#define IHCK  128          // IHC FIR taps

#define MODL  441
#define MODC  50           // MODL*MODC == T_

// ---- workspace layout (in floats) ----
#define OFF_H1    0                      // 1024
#define OFF_G5    1024                   // 256
#define OFF_X1    1280                   // 176512 (B_*T_=176400)
#define OFF_HW    (OFF_X1 + 176512)      // 5468416 (BN*T_=5468400)
#define OFF_ENV   (OFF_HW + 5468416)     // 5468416
#define OFF_AD    OFF_HW                 // alias: hw dead after IHC
#define OFF_SEND  (OFF_ENV + 5468416)    // 297600 floats (float2 x 148800)
#define OFF_SINIT (OFF_SEND + 297600)    // 297600
// total = 11,709,824 floats = 46.9 MB

struct ScanP {
  float a1[5], b0[5], factor[5], efl2[5], offset[5], init[5], rinit[5];
  float minlvl, corr, scale;
};
struct ModP {
  float pre[12], pim[12], pb0[12], pLre[12], pLim[12];
  float att;
};

// ---------- combined hp*me FIR (length 1023) ----------
__global__ void k_h1(const float* __restrict__ hp, const float* __restrict__ me,
                     float* __restrict__ h1) {
  int k = blockIdx.x * blockDim.x + threadIdx.x;
  if (k >= H1LEN) return;
  int j0 = max(0, k - (LH - 1));
  int j1 = min(LH - 1, k);
  float acc = 0.f;
  for (int j = j0; j <= j1; ++j) acc += hp[j] * me[k - j];
  h1[k] = acc;
}

// ---------- IHC LP^5 impulse response: (1-a)^5 * C(k+4,4) * a^k ----------
__global__ void k_g5(float l2a, float c5, float* __restrict__ g5) {
  int k = threadIdx.x;  // 128
  float kf = (float)k;
  float binom = (kf + 1.f) * (kf + 2.f) * (kf + 3.f) * (kf + 4.f) * (1.0f / 24.0f);
  g5[k] = c5 * binom * exp2f(kf * l2a);
}

// ---------- conv1: x (*) h1 -> x1,  K=1023, 1 output/thread ----------
__global__ void k_conv1(const float* __restrict__ x, const float* __restrict__ h1,
                        float* __restrict__ x1) {
  __shared__ float xs[256 + 1022];  // 1278
  __shared__ float hs[H1LEN];
  int b = blockIdx.y;
  int t0 = blockIdx.x * 256;
  const float* xb = x + b * T_;
  for (int i = threadIdx.x; i < 1278; i += 256) {
    int g = t0 - 1022 + i;
    xs[i] = (g >= 0 && g < T_) ? xb[g] : 0.f;
  }
  for (int i = threadIdx.x; i < H1LEN; i += 256) hs[i] = h1[i];
  __syncthreads();
  int t = t0 + threadIdx.x;
  if (t >= T_) return;
  float acc = 0.f;
  for (int k = 0; k < H1LEN; ++k) acc = fmaf(hs[k], xs[threadIdx.x + 1022 - k], acc);
  x1[b * T_ + t] = acc;
}

// ---------- conv2: x1 (*) gt[n] -> hw = relu(y), K=2048, 4 outputs/thread ----------
__global__ __launch_bounds__(C2THR) void k_conv2(const float* __restrict__ x1,
                                                 const float* __restrict__ gt,
                                                 float* __restrict__ hw) {
  const int H = LG - 1;  // 2047
  __shared__ __align__(16) float xs[C2T + LG];  // 2560
  __shared__ __align__(16) float hs[LG];
  int n = blockIdx.y % NCH, b = blockIdx.y / NCH;
  int t0 = blockIdx.x * C2T;
  const float* xb = x1 + b * T_;
  for (int i = threadIdx.x; i < C2T + LG; i += C2THR) {
    int g = t0 - H + i;
    xs[i] = (g >= 0 && g < T_) ? xb[g] : 0.f;
  }
  for (int i = threadIdx.x; i < LG; i += C2THR) hs[i] = gt[n * LG + i];
  __syncthreads();
  int base = threadIdx.x * 4;
  float a0 = 0.f, a1 = 0.f, a2 = 0.f, a3 = 0.f;
  float4 hi = *(const float4*)&xs[base + H + 1];  // [base+H+1 .. base+H+4]
  for (int k4 = 0; k4 < LG / 4; ++k4) {
    int k = k4 * 4;
    float4 lo = *(const float4*)&xs[base + H - 3 - k];  // [base+H-3-k .. base+H-k]
    float4 hh = *(const float4*)&hs[k];
    a0 = fmaf(hh.x, lo.w, a0); a1 = fmaf(hh.x, hi.x, a1); a2 = fmaf(hh.x, hi.y, a2); a3 = fmaf(hh.x, hi.z, a3);
    a0 = fmaf(hh.y, lo.z, a0); a1 = fmaf(hh.y, lo.w, a1); a2 = fmaf(hh.y, hi.x, a2); a3 = fmaf(hh.y, hi.y, a3);
    a0 = fmaf(hh.z, lo.y, a0); a1 = fmaf(hh.z, lo.z, a1); a2 = fmaf(hh.z, lo.w, a2); a3 = fmaf(hh.z, hi.x, a3);
    a0 = fmaf(hh.w, lo.x, a0); a1 = fmaf(hh.w, lo.y, a1); a2 = fmaf(hh.w, lo.z, a2); a3 = fmaf(hh.w, lo.w, a3);
    hi = lo;
  }
  float* o = hw + (size_t)(b * NCH + n) * T_;
  int t = t0 + base;
  if (t + 0 < T_) o[t + 0] = fmaxf(a0, 0.f);
  if (t + 1 < T_) o[t + 1] = fmaxf(a1, 0.f);
  if (t + 2 < T_) o[t + 2] = fmaxf(a2, 0.f);
  if (t + 3 < T_) o[t + 3] = fmaxf(a3, 0.f);
}

// ---------- IHC FIR: hw (*) g5 -> env, K=128, 4 outputs/thread ----------
__global__ __launch_bounds__(C2THR) void k_ihc(const float* __restrict__ hw,
                                               const float* __restrict__ g5,
                                               float* __restrict__ env) {
  const int H = IHCK - 1;  // 127
  __shared__ __align__(16) float xs[C2T + IHCK];  // 640
  __shared__ __align__(16) float hs[IHCK];
  int bn = blockIdx.y;
  int t0 = blockIdx.x * C2T;
  const float* xb = hw + (size_t)bn * T_;
  for (int i = threadIdx.x; i < C2T + IHCK; i += C2THR) {
    int g = t0 - H + i;
    xs[i] = (g >= 0 && g < T_) ? xb[g] : 0.f;
  }
  if (threadIdx.x < IHCK) hs[threadIdx.x] = g5[threadIdx.x];
  __syncthreads();
  int base = threadIdx.x * 4;
  float a0 = 0.f, a1 = 0.f, a2 = 0.f, a3 = 0.f;
  float4 hi = *(const float4*)&xs[base + H + 1];
  for (int k4 = 0; k4 < IHCK / 4; ++k4) {
    int k = k4 * 4;
    float4 lo = *(const float4*)&xs[base + H - 3 - k];
    float4 hh = *(const float4*)&hs[k];
    a0 = fmaf(hh.x, lo.w, a0); a1 = fmaf(hh.x, hi.x, a1); a2 = fmaf(hh.x, hi.y, a2); a3 = fmaf(hh.x, hi.z, a3);
    a0 = fmaf(hh.y, lo.z, a0); a1 = fmaf(hh.y, lo.w, a1); a2 = fmaf(hh.y, hi.x, a2); a3 = fmaf(hh.y, hi.y, a3);
    a0 = fmaf(hh.z, lo.y, a0); a1 = fmaf(hh.z, lo.z, a1); a2 = fmaf(hh.z, lo.w, a2); a3 = fmaf(hh.z, hi.x, a3);
    a0 = fmaf(hh.w, lo.x, a0); a1 = fmaf(hh.w, lo.y, a1); a2 = fmaf(hh.w, lo.z, a2); a3 = fmaf(hh.w, lo.w, a3);
    hi = lo;
  }
  float* o = env + (size_t)bn * T_;
  int t = t0 + base;
  if (t + 0 < T_) o[t + 0] = a0;
  if (t + 1 < T_) o[t + 1] = a1;
  if (t + 2 < T_) o[t + 2] = a2;
  if (t + 3 < T_) o[t + 3] = a3;
}

// ---------- adaptation loops: systolic 5-lane pipeline per sequence ----------
// Lane layout per wave: 4 DPP rows of 16 lanes; each row holds 3 sequences x 5
// stages (lane q = s_local*5 + j, q==15 idle). Stage j at group k processes
// t = k - j; tmp passes stage j-1 -> j via DPP row_shr:1 (never crosses rows).
// Critical path per group = ONE loop's chain (~40 cy) instead of five.
__device__ __forceinline__ float dpp_shr1(float v) {
  return __int_as_float(__builtin_amdgcn_update_dpp(
      0, __float_as_int(v), 0x111, 0xF, 0xF, true));  // row_shr:1, bound->0
}

__global__ __launch_bounds__(64) void k_scan(const float* __restrict__ env,
                                             float* __restrict__ ad, ScanP p) {
  const int lane = threadIdx.x;
  const int row = lane >> 4, q = lane & 15;
  const int sl = q / 5;              // 0..3 (3 = idle dummy)
  const int j  = q - sl * 5;         // stage 0..4
  int seq = blockIdx.x * 12 + row * 3 + sl;
  const bool valid = (sl < 3) && (seq < BN);
  const int seq_c = valid ? seq : 0;                 // clamp for safe addressing
  const float* e = env + (size_t)seq_c * T_;
  float* o = ad + (size_t)seq_c * T_;
  const bool is0 = (j == 0);
  const bool is4v = (j == 4) && valid;

#define SEL5(A) (j==0 ? (A)[0] : j==1 ? (A)[1] : j==2 ? (A)[2] : j==3 ? (A)[3] : (A)[4])
  const float A1  = SEL5(p.a1),   B0  = SEL5(p.b0), FAC = SEL5(p.factor);
  const float EF  = SEL5(p.efl2), NEF = -EF,        NOFF = -SEL5(p.offset);
  float st = SEL5(p.init);
  float r  = SEL5(p.rinit);
#undef SEL5
  const float SC = p.scale, NCS = -p.corr * p.scale, ML = p.minlvl;

  float tmp = 0.f;

  // one pipeline group; state update guarded (fill phase: stage j idle until k>=j)
#define STEP_FILL(EV, K)                                                      \
  {                                                                           \
    float up  = dpp_shr1(tmp);                                                \
    float tin = is0 ? (EV) : up;                                              \
    float v   = tin * r;                                                      \
    float ex  = __builtin_amdgcn_exp2f(fmaf(EF, v, NEF));                     \
    float lim = fmaf(FAC, __builtin_amdgcn_rcpf(1.0f + ex), NOFF);            \
    tmp = (v > 1.0f) ? lim : v;                                               \
    float nst = fmaf(A1, st, B0 * tmp);                                       \
    st = ((K) >= j) ? nst : st;                                               \
    r  = __builtin_amdgcn_rcpf(st);                                           \
  }

#define STEP(EV, KK)                                                          \
  {                                                                           \
    float up  = dpp_shr1(tmp);                                                \
    float tin = is0 ? (EV) : up;                                              \
    float v   = tin * r;                                                      \
    float ex  = __builtin_amdgcn_exp2f(fmaf(EF, v, NEF));                     \
    float lim = fmaf(FAC, __builtin_amdgcn_rcpf(1.0f + ex), NOFF);            \
    tmp = (v > 1.0f) ? lim : v;                                               \
    st = fmaf(A1, st, B0 * tmp);                                              \
    r  = __builtin_amdgcn_rcpf(st);                                           \
    float ov = fmaf(tmp, SC, NCS);                                            \
    if (is4v) o[(KK) - 4] = ov;                                               \
  }

  // prologue: env values for groups 0..11 (fmax applied at load, off chain)
  float c0 = fmaxf(e[0], ML), c1 = fmaxf(e[1], ML), c2 = fmaxf(e[2], ML), c3 = fmaxf(e[3], ML);
  float d0 = fmaxf(e[4], ML), d1 = fmaxf(e[5], ML), d2 = fmaxf(e[6], ML), d3 = fmaxf(e[7], ML);
  float g0 = fmaxf(e[8], ML), g1 = fmaxf(e[9], ML), g2 = fmaxf(e[10], ML), g3 = fmaxf(e[11], ML);

  // pipeline fill: groups 0..3 (no stores; t=k-4 < 0)
  STEP_FILL(c0, 0) STEP_FILL(c1, 1) STEP_FILL(c2, 2) STEP_FILL(c3, 3)

  // main: groups 4..22051 (stage-4 t = 0..22047), prefetch distance 8 groups
  for (int k = 4; k < 4 + 22048; k += 4) {
    c0 = d0; c1 = d1; c2 = d2; c3 = d3;
    d0 = g0; d1 = g1; d2 = g2; d3 = g3;
    int kp = k + 8;  // max e index 22059 < T_+? stays inside ws (checked)
    g0 = fmaxf(e[kp], ML); g1 = fmaxf(e[kp + 1], ML);
    g2 = fmaxf(e[kp + 2], ML); g3 = fmaxf(e[kp + 3], ML);
    STEP(c0, k) STEP(c1, k + 1) STEP(c2, k + 2) STEP(c3, k + 3)
  }
  // drain: groups 22052..22053 produce stage-4 t = 22048, 22049
  STEP(0.f, 22052) STEP(0.f, 22053)
#undef STEP
#undef STEP_FILL
}

// ---------- modulation filterbank, chunk-parallel linear scan ----------
__global__ void k_modA(const float* __restrict__ ad, float2* __restrict__ send, ModP mp) {
  int id = blockIdx.x * 256 + threadIdx.x;
  if (id >= MODC * BN * MM) return;
  int m = id % MM, bn = (id / MM) % BN, c = id / (MM * BN);
  const float* a = ad + (size_t)bn * T_ + c * MODL;
  float pre = mp.pre[m], pim = mp.pim[m], b0 = mp.pb0[m];
  float sre = 0.f, sim = 0.f;
  for (int i = 0; i < MODL; ++i) {
    float xv = a[i];
    float nre = fmaf(pre, sre, fmaf(-pim, sim, b0 * xv));
    sim = fmaf(pre, sim, pim * sre);
    sre = nre;
  }
  send[id] = make_float2(sre, sim);
}

__global__ void k_modB(const float2* __restrict__ send, float2* __restrict__ sinit, ModP mp) {
  int id = blockIdx.x * blockDim.x + threadIdx.x;
  if (id >= BN * MM) return;
  int m = id % MM;
  float pLre = mp.pLre[m], pLim = mp.pLim[m];
  float Sre = 0.f, Sim = 0.f;
  for (int c = 0; c < MODC; ++c) {
    int idx = c * BN * MM + id;
    sinit[idx] = make_float2(Sre, Sim);
    float2 se = send[idx];
    float nre = pLre * Sre - pLim * Sim + se.x;
    Sim = pLre * Sim + pLim * Sre + se.y;
    Sre = nre;
  }
}

__global__ void k_modC(const float* __restrict__ ad, const float2* __restrict__ sinit,
                       float* __restrict__ out, ModP mp) {
  int id = blockIdx.x * 256 + threadIdx.x;
  if (id >= MODC * BN * MM) return;
  int m = id % MM, bn = (id / MM) % BN, c = id / (MM * BN);
  const float* a = ad + (size_t)bn * T_ + c * MODL;
  float* o = out + ((size_t)bn * MM + m) * T_ + c * MODL;
  float2 s0 = sinit[id];
  float sre = s0.x, sim = s0.y;
  float pre = mp.pre[m], pim = mp.pim[m], b0 = mp.pb0[m], att = mp.att;
  bool low = (m < 3);  // mfc <= 10 Hz
  for (int i = 0; i < MODL; ++i) {
    float xv = a[i];
    float nre = fmaf(pre, sre, fmaf(-pim, sim, b0 * xv));
    sim = fmaf(pre, sim, pim * sre);
    sre = nre;
    float mag = att * sqrtf(fmaf(sre, sre, fmaf(sim, sim, 1e-12f)));
    o[i] = low ? sre : mag;
  }
}

extern "C" void kernel_launch(void* const* d_in, const int* in_sizes, int n_in,
                              void* d_out, int out_size, void* d_ws, size_t ws_size,
                              hipStream_t stream) {
  const float* x  = (const float*)d_in[0];
  const float* hp = (const float*)d_in[1];
  const float* me = (const float*)d_in[2];
  const float* gt = (const float*)d_in[3];
  float* ws  = (float*)d_ws;
  float* out = (float*)d_out;

  // ---- host-side constant computation (double precision) ----
  ScanP sp;
  const double taus[5] = {0.005, 0.05, 0.129, 0.253, 0.5};
  for (int j = 0; j < 5; ++j) {
    double a1 = exp(-1.0 / (FS_ * taus[j]));
    double init = pow(1e-5, pow(2.0, -(double)(j + 1)));
    double maxv = (1.0 - init * init) * 5.0 - 1.0;
    sp.a1[j] = (float)a1;
    sp.b0[j] = (float)(1.0 - a1);
    sp.factor[j] = (float)(2.0 * maxv);
    sp.efl2[j] = (float)(-2.0 / maxv * 1.4426950408889634);  // expfac * log2(e)
    sp.offset[j] = (float)(maxv - 1.0);
    sp.init[j] = (float)init;
    sp.rinit[j] = (float)(1.0 / init);
  }
  sp.minlvl = 1e-5f;
  double corr = pow(1e-5, pow(2.0, -5.0));
  sp.corr = (float)corr;
  sp.scale = (float)(100.0 / (1.0 - corr));

  ModP mp;
  const double mfc[12] = {2.5, 5.0, 10.0, 16.7, 27.8, 46.3, 77.2, 128.6, 214.3, 357.2, 595.4, 992.3};
  for (int m = 0; m < 12; ++m) {
    double r = exp(-M_PI * (mfc[m] / 2.0) / FS_);
    double th = 2.0 * M_PI * mfc[m] / FS_;
    mp.pre[m] = (float)(r * cos(th));
    mp.pim[m] = (float)(r * sin(th));
    mp.pb0[m] = (float)(1.0 - r);
    double rL = pow(r, (double)MODL);
    mp.pLre[m] = (float)(rL * cos((double)MODL * th));
    mp.pLim[m] = (float)(rL * sin((double)MODL * th));
  }
  mp.att = (float)(1.0 / sqrt(2.0));

  double alp = exp(-2.0 * M_PI * 2000.0 / FS_);
  float l2a = (float)(log(alp) * 1.4426950408889634);
  float c5  = (float)pow(1.0 - alp, 5.0);

  float* h1  = ws + OFF_H1;
  float* g5  = ws + OFF_G5;
  float* x1  = ws + OFF_X1;
  float* hw  = ws + OFF_HW;
  float* env = ws + OFF_ENV;
  float* ad  = ws + OFF_AD;  // aliases hw (dead after IHC)
  float2* send  = (float2*)(ws + OFF_SEND);
  float2* sinit = (float2*)(ws + OFF_SINIT);

  k_h1<<<dim3(2), dim3(512), 0, stream>>>(hp, me, h1);
  k_g5<<<dim3(1), dim3(128), 0, stream>>>(l2a, c5, g5);
  k_conv1<<<dim3(87, B_), dim3(256), 0, stream>>>(x, h1, x1);
  k_conv2<<<dim3((T_ + C2T - 1) / C2T, BN), dim3(C2THR), 0, stream>>>(x1, gt, hw);
  k_ihc<<<dim3((T_ + C2T - 1) / C2T, BN), dim3(C2THR), 0, stream>>>(hw, g5, env);
  k_scan<<<dim3(21), dim3(64), 0, stream>>>(env, ad, sp);  // 12 seqs/wave, 5-lane systolic
  int nmod = MODC * BN * MM;
  k_modA<<<dim3((nmod + 255) / 256), dim3(256), 0, stream>>>(ad, send, mp);
  k_modB<<<dim3((BN * MM + 255) / 256), dim3(256), 0, stream>>>(send, sinit, mp);
  k_modC<<<dim3((nmod + 255) / 256), dim3(256), 0, stream>>>(ad, sinit, out, mp);
}

// Round 3
// 2599.794 us; speedup vs baseline: 2.9271x; 1.1620x over previous
//
#include <hip/hip_runtime.h>
#include <math.h>

#define FS_   44100.0
#define B_    8
#define T_    22050
#define NCH   31
#define LG    2048
#define LH    512
#define MM    12
#define BN    248          // B_*NCH

#define H1LEN 1023         // LH+LH-1

#define C2T   512          // t-tile for conv2/ihc
#define C2THR 128          // threads (each does 4 consecutive t)

#define IHCK  128          // IHC FIR taps

#define MODL  441
#define MODC  50           // MODL*MODC == T_

#define NBLK  62           // k_scan blocks: 4 seqs per wave
#define TQ    5520         // env time-quads per seq (22080/4, padded)
#define ADP   22052        // ad row pitch (multiple of 4 floats -> 16B rows)

// ---- workspace layout (in floats) ----
#define OFF_H1    0                       // 1024
#define OFF_G5    1024                    // 256
#define OFF_X1    1280                    // 176400 (pad to 177696)
#define OFF_HW    177696                  // hw: BN*T_ = 5468400 ; ad alias: BN*ADP = 5468896
#define OFF_AD    OFF_HW
#define OFF_ENV   (OFF_HW + 5468896)      // 5646592 ; env interleaved: NBLK*TQ*16 = 5475840
#define OFF_SEND  (OFF_ENV + 5475840)     // 11122432 ; 297600
#define OFF_SINIT (OFF_SEND + 297600)     // 11420032 ; 297600 ; total 11717632 fl = 46.9 MB

struct ScanP {
  float a1[5], b0[5], factor[5], efl2[5], offset[5], init[5], rinit[5];
  float minlvl, corr, scale;
};
struct ModP {
  float pre[12], pim[12], pb0[12], pLre[12], pLim[12];
  float att;
};

// ---------- combined hp*me FIR (length 1023) ----------
__global__ void k_h1(const float* __restrict__ hp, const float* __restrict__ me,
                     float* __restrict__ h1) {
  int k = blockIdx.x * blockDim.x + threadIdx.x;
  if (k >= H1LEN) return;
  int j0 = max(0, k - (LH - 1));
  int j1 = min(LH - 1, k);
  float acc = 0.f;
  for (int j = j0; j <= j1; ++j) acc += hp[j] * me[k - j];
  h1[k] = acc;
}

// ---------- IHC LP^5 impulse response: (1-a)^5 * C(k+4,4) * a^k ----------
__global__ void k_g5(float l2a, float c5, float* __restrict__ g5) {
  int k = threadIdx.x;  // 128
  float kf = (float)k;
  float binom = (kf + 1.f) * (kf + 2.f) * (kf + 3.f) * (kf + 4.f) * (1.0f / 24.0f);
  g5[k] = c5 * binom * exp2f(kf * l2a);
}

// ---------- conv1: x (*) h1 -> x1,  K=1023, 1 output/thread ----------
__global__ void k_conv1(const float* __restrict__ x, const float* __restrict__ h1,
                        float* __restrict__ x1) {
  __shared__ float xs[256 + 1022];  // 1278
  __shared__ float hs[H1LEN];
  int b = blockIdx.y;
  int t0 = blockIdx.x * 256;
  const float* xb = x + b * T_;
  for (int i = threadIdx.x; i < 1278; i += 256) {
    int g = t0 - 1022 + i;
    xs[i] = (g >= 0 && g < T_) ? xb[g] : 0.f;
  }
  for (int i = threadIdx.x; i < H1LEN; i += 256) hs[i] = h1[i];
  __syncthreads();
  int t = t0 + threadIdx.x;
  if (t >= T_) return;
  float acc = 0.f;
  for (int k = 0; k < H1LEN; ++k) acc = fmaf(hs[k], xs[threadIdx.x + 1022 - k], acc);
  x1[b * T_ + t] = acc;
}

// ---------- conv2: x1 (*) gt[n] -> hw = relu(y), K=2048, 4 outputs/thread ----------
__global__ __launch_bounds__(C2THR) void k_conv2(const float* __restrict__ x1,
                                                 const float* __restrict__ gt,
                                                 float* __restrict__ hw) {
  const int H = LG - 1;  // 2047
  __shared__ __align__(16) float xs[C2T + LG];  // 2560
  __shared__ __align__(16) float hs[LG];
  int n = blockIdx.y % NCH, b = blockIdx.y / NCH;
  int t0 = blockIdx.x * C2T;
  const float* xb = x1 + b * T_;
  for (int i = threadIdx.x; i < C2T + LG; i += C2THR) {
    int g = t0 - H + i;
    xs[i] = (g >= 0 && g < T_) ? xb[g] : 0.f;
  }
  for (int i = threadIdx.x; i < LG; i += C2THR) hs[i] = gt[n * LG + i];
  __syncthreads();
  int base = threadIdx.x * 4;
  float a0 = 0.f, a1 = 0.f, a2 = 0.f, a3 = 0.f;
  float4 hi = *(const float4*)&xs[base + H + 1];  // [base+H+1 .. base+H+4]
  for (int k4 = 0; k4 < LG / 4; ++k4) {
    int k = k4 * 4;
    float4 lo = *(const float4*)&xs[base + H - 3 - k];  // [base+H-3-k .. base+H-k]
    float4 hh = *(const float4*)&hs[k];
    a0 = fmaf(hh.x, lo.w, a0); a1 = fmaf(hh.x, hi.x, a1); a2 = fmaf(hh.x, hi.y, a2); a3 = fmaf(hh.x, hi.z, a3);
    a0 = fmaf(hh.y, lo.z, a0); a1 = fmaf(hh.y, lo.w, a1); a2 = fmaf(hh.y, hi.x, a2); a3 = fmaf(hh.y, hi.y, a3);
    a0 = fmaf(hh.z, lo.y, a0); a1 = fmaf(hh.z, lo.z, a1); a2 = fmaf(hh.z, lo.w, a2); a3 = fmaf(hh.z, hi.x, a3);
    a0 = fmaf(hh.w, lo.x, a0); a1 = fmaf(hh.w, lo.y, a1); a2 = fmaf(hh.w, lo.z, a2); a3 = fmaf(hh.w, lo.w, a3);
    hi = lo;
  }
  float* o = hw + (size_t)(b * NCH + n) * T_;
  int t = t0 + base;
  if (t + 0 < T_) o[t + 0] = fmaxf(a0, 0.f);
  if (t + 1 < T_) o[t + 1] = fmaxf(a1, 0.f);
  if (t + 2 < T_) o[t + 2] = fmaxf(a2, 0.f);
  if (t + 3 < T_) o[t + 3] = fmaxf(a3, 0.f);
}

// ---------- IHC FIR: hw (*) g5 -> env (interleaved), K=128, 4 outputs/thread ----------
// env layout: [blk=bn/4][tq=t/4][s=bn%4][tt=t%4]  (one float4 store per thread)
__global__ __launch_bounds__(C2THR) void k_ihc(const float* __restrict__ hw,
                                               const float* __restrict__ g5,
                                               float* __restrict__ env) {
  const int H = IHCK - 1;  // 127
  __shared__ __align__(16) float xs[C2T + IHCK];  // 640
  __shared__ __align__(16) float hs[IHCK];
  int bn = blockIdx.y;
  int t0 = blockIdx.x * C2T;
  const float* xb = hw + (size_t)bn * T_;
  for (int i = threadIdx.x; i < C2T + IHCK; i += C2THR) {
    int g = t0 - H + i;
    xs[i] = (g >= 0 && g < T_) ? xb[g] : 0.f;
  }
  if (threadIdx.x < IHCK) hs[threadIdx.x] = g5[threadIdx.x];
  __syncthreads();
  int base = threadIdx.x * 4;
  float a0 = 0.f, a1 = 0.f, a2 = 0.f, a3 = 0.f;
  float4 hi = *(const float4*)&xs[base + H + 1];
  for (int k4 = 0; k4 < IHCK / 4; ++k4) {
    int k = k4 * 4;
    float4 lo = *(const float4*)&xs[base + H - 3 - k];
    float4 hh = *(const float4*)&hs[k];
    a0 = fmaf(hh.x, lo.w, a0); a1 = fmaf(hh.x, hi.x, a1); a2 = fmaf(hh.x, hi.y, a2); a3 = fmaf(hh.x, hi.z, a3);
    a0 = fmaf(hh.y, lo.z, a0); a1 = fmaf(hh.y, lo.w, a1); a2 = fmaf(hh.y, hi.x, a2); a3 = fmaf(hh.y, hi.y, a3);
    a0 = fmaf(hh.z, lo.y, a0); a1 = fmaf(hh.z, lo.z, a1); a2 = fmaf(hh.z, lo.w, a2); a3 = fmaf(hh.z, hi.x, a3);
    a0 = fmaf(hh.w, lo.x, a0); a1 = fmaf(hh.w, lo.y, a1); a2 = fmaf(hh.w, lo.z, a2); a3 = fmaf(hh.w, lo.w, a3);
    hi = lo;
  }
  int t = t0 + base;
  if (t < T_) {  // last quad may carry 2 junk lanes (t=22050/22051) -> never affect stored outputs
    int blk = bn >> 2, s = bn & 3, tq = t >> 2;
    float4* o4 = (float4*)(env + ((size_t)(blk * TQ + tq) * 4 + s) * 4);
    *o4 = make_float4(a0, a1, a2, a3);
  }
}

// ---------- adaptation loops: systolic 5-lane pipeline, 1 seq per 16-lane row ----------
// Lane q (=lane&15) = stage j for q<5; q>=5 idle. Stage j at group k processes t=k-j.
// tmp passes j-1 -> j via DPP row_shr:1; lane q=0 (stage 0) gets `old` = env value
// (bound_ctrl=false) -- no select on the recurrence chain.
__global__ __launch_bounds__(64) void k_scan(const float* __restrict__ env,
                                             float* __restrict__ ad, ScanP p) {
  const int lane = threadIdx.x;
  const int row = lane >> 4, q = lane & 15;
  const int seq = blockIdx.x * 4 + row;
  const bool is4 = (q == 4);
  const float* eb = env + (size_t)blockIdx.x * TQ * 16 + row * 4;  // +tq*16 per quad
  float* o = ad + (size_t)seq * ADP;

#define SEL5(A) (q==0 ? (A)[0] : q==1 ? (A)[1] : q==2 ? (A)[2] : q==3 ? (A)[3] : (A)[4])
  const float A1  = SEL5(p.a1),   B0  = SEL5(p.b0), FAC = SEL5(p.factor);
  const float EF  = SEL5(p.efl2), NEF = -EF,        NOFF = -SEL5(p.offset);
  float st = SEL5(p.init);
  float r  = SEL5(p.rinit);
#undef SEL5
  const float SC = p.scale, NCS = -p.corr * p.scale, ML = p.minlvl;

  float tmp = 0.f;
  float o0 = 0.f, o1 = 0.f, o2 = 0.f, o3 = 0.f;

#define BODY(EV)                                                              \
    float evc = fmaxf((EV), ML);                                              \
    float tin = __int_as_float(__builtin_amdgcn_update_dpp(                   \
        __float_as_int(evc), __float_as_int(tmp), 0x111, 0xF, 0xF, false));   \
    float v   = tin * r;                                                      \
    float ex  = __builtin_amdgcn_exp2f(fmaf(EF, v, NEF));                     \
    float lim = fmaf(FAC, __builtin_amdgcn_rcpf(1.0f + ex), NOFF);            \
    tmp = (v > 1.0f) ? lim : v;

#define STEP_FILL(EV, K)                                                      \
  { BODY(EV)                                                                  \
    float nst = fmaf(A1, st, B0 * tmp);                                       \
    st = ((K) >= q) ? nst : st;                                               \
    r  = __builtin_amdgcn_rcpf(st); }

#define STEP(EV, OSLOT)                                                       \
  { BODY(EV)                                                                  \
    st = fmaf(A1, st, B0 * tmp);                                              \
    r  = __builtin_amdgcn_rcpf(st);                                           \
    OSLOT = fmaf(tmp, SC, NCS); }

  // quad 0 (groups 0..3) + prefetch quads 1..4
  float4 cq = *(const float4*)(eb + 0 * 16);
  float4 c  = *(const float4*)(eb + 1 * 16);
  float4 d  = *(const float4*)(eb + 2 * 16);
  float4 g  = *(const float4*)(eb + 3 * 16);
  float4 h  = *(const float4*)(eb + 4 * 16);

  // pipeline fill: groups 0..3 (stage-4 t < 0, no stores)
  STEP_FILL(cq.x, 0) STEP_FILL(cq.y, 1) STEP_FILL(cq.z, 2) STEP_FILL(cq.w, 3)

  // main: groups 4..22051 (stage-4 t = 0..22047); prefetch distance 4 iters = 16 groups
  for (int k = 4; k <= 22048; k += 4) {
    float4 cc = c; c = d; d = g; g = h;
    h = *(const float4*)(eb + (size_t)(k / 4 + 4) * 16);
    STEP(cc.x, o0) STEP(cc.y, o1) STEP(cc.z, o2) STEP(cc.w, o3)
    if (is4) *(float4*)(o + (k - 4)) = make_float4(o0, o1, o2, o3);
  }
  // drain: groups 22052, 22053 -> t = 22048, 22049 (+2 pad floats, row pitch 22052)
  STEP(0.f, o0) STEP(0.f, o1)
  if (is4) *(float4*)(o + 22048) = make_float4(o0, o1, o2, o3);
#undef STEP
#undef STEP_FILL
#undef BODY
}

// ---------- modulation filterbank, chunk-parallel linear scan ----------
__global__ void k_modA(const float* __restrict__ ad, float2* __restrict__ send, ModP mp) {
  int id = blockIdx.x * 256 + threadIdx.x;
  if (id >= MODC * BN * MM) return;
  int m = id % MM, bn = (id / MM) % BN, c = id / (MM * BN);
  const float* a = ad + (size_t)bn * ADP + c * MODL;
  float pre = mp.pre[m], pim = mp.pim[m], b0 = mp.pb0[m];
  float sre = 0.f, sim = 0.f;
  for (int i = 0; i < MODL; ++i) {
    float xv = a[i];
    float nre = fmaf(pre, sre, fmaf(-pim, sim, b0 * xv));
    sim = fmaf(pre, sim, pim * sre);
    sre = nre;
  }
  send[id] = make_float2(sre, sim);
}

__global__ void k_modB(const float2* __restrict__ send, float2* __restrict__ sinit, ModP mp) {
  int id = blockIdx.x * blockDim.x + threadIdx.x;
  if (id >= BN * MM) return;
  int m = id % MM;
  float pLre = mp.pLre[m], pLim = mp.pLim[m];
  float Sre = 0.f, Sim = 0.f;
  for (int c = 0; c < MODC; ++c) {
    int idx = c * BN * MM + id;
    sinit[idx] = make_float2(Sre, Sim);
    float2 se = send[idx];
    float nre = pLre * Sre - pLim * Sim + se.x;
    Sim = pLre * Sim + pLim * Sre + se.y;
    Sre = nre;
  }
}

__global__ void k_modC(const float* __restrict__ ad, const float2* __restrict__ sinit,
                       float* __restrict__ out, ModP mp) {
  int id = blockIdx.x * 256 + threadIdx.x;
  if (id >= MODC * BN * MM) return;
  int m = id % MM, bn = (id / MM) % BN, c = id / (MM * BN);
  const float* a = ad + (size_t)bn * ADP + c * MODL;
  float* o = out + ((size_t)bn * MM + m) * T_ + c * MODL;
  float2 s0 = sinit[id];
  float sre = s0.x, sim = s0.y;
  float pre = mp.pre[m], pim = mp.pim[m], b0 = mp.pb0[m], att = mp.att;
  bool low = (m < 3);  // mfc <= 10 Hz
  for (int i = 0; i < MODL; ++i) {
    float xv = a[i];
    float nre = fmaf(pre, sre, fmaf(-pim, sim, b0 * xv));
    sim = fmaf(pre, sim, pim * sre);
    sre = nre;
    float mag = att * sqrtf(fmaf(sre, sre, fmaf(sim, sim, 1e-12f)));
    o[i] = low ? sre : mag;
  }
}

extern "C" void kernel_launch(void* const* d_in, const int* in_sizes, int n_in,
                              void* d_out, int out_size, void* d_ws, size_t ws_size,
                              hipStream_t stream) {
  const float* x  = (const float*)d_in[0];
  const float* hp = (const float*)d_in[1];
  const float* me = (const float*)d_in[2];
  const float* gt = (const float*)d_in[3];
  float* ws  = (float*)d_ws;
  float* out = (float*)d_out;

  // ---- host-side constant computation (double precision) ----
  ScanP sp;
  const double taus[5] = {0.005, 0.05, 0.129, 0.253, 0.5};
  for (int j = 0; j < 5; ++j) {
    double a1 = exp(-1.0 / (FS_ * taus[j]));
    double init = pow(1e-5, pow(2.0, -(double)(j + 1)));
    double maxv = (1.0 - init * init) * 5.0 - 1.0;
    sp.a1[j] = (float)a1;
    sp.b0[j] = (float)(1.0 - a1);
    sp.factor[j] = (float)(2.0 * maxv);
    sp.efl2[j] = (float)(-2.0 / maxv * 1.4426950408889634);  // expfac * log2(e)
    sp.offset[j] = (float)(maxv - 1.0);
    sp.init[j] = (float)init;
    sp.rinit[j] = (float)(1.0 / init);
  }
  sp.minlvl = 1e-5f;
  double corr = pow(1e-5, pow(2.0, -5.0));
  sp.corr = (float)corr;
  sp.scale = (float)(100.0 / (1.0 - corr));

  ModP mp;
  const double mfc[12] = {2.5, 5.0, 10.0, 16.7, 27.8, 46.3, 77.2, 128.6, 214.3, 357.2, 595.4, 992.3};
  for (int m = 0; m < 12; ++m) {
    double r = exp(-M_PI * (mfc[m] / 2.0) / FS_);
    double th = 2.0 * M_PI * mfc[m] / FS_;
    mp.pre[m] = (float)(r * cos(th));
    mp.pim[m] = (float)(r * sin(th));
    mp.pb0[m] = (float)(1.0 - r);
    double rL = pow(r, (double)MODL);
    mp.pLre[m] = (float)(rL * cos((double)MODL * th));
    mp.pLim[m] = (float)(rL * sin((double)MODL * th));
  }
  mp.att = (float)(1.0 / sqrt(2.0));

  double alp = exp(-2.0 * M_PI * 2000.0 / FS_);
  float l2a = (float)(log(alp) * 1.4426950408889634);
  float c5  = (float)pow(1.0 - alp, 5.0);

  float* h1  = ws + OFF_H1;
  float* g5  = ws + OFF_G5;
  float* x1  = ws + OFF_X1;
  float* hw  = ws + OFF_HW;
  float* env = ws + OFF_ENV;
  float* ad  = ws + OFF_AD;  // aliases hw (dead after IHC)
  float2* send  = (float2*)(ws + OFF_SEND);
  float2* sinit = (float2*)(ws + OFF_SINIT);

  k_h1<<<dim3(2), dim3(512), 0, stream>>>(hp, me, h1);
  k_g5<<<dim3(1), dim3(128), 0, stream>>>(l2a, c5, g5);
  k_conv1<<<dim3(87, B_), dim3(256), 0, stream>>>(x, h1, x1);
  k_conv2<<<dim3((T_ + C2T - 1) / C2T, BN), dim3(C2THR), 0, stream>>>(x1, gt, hw);
  k_ihc<<<dim3((T_ + C2T - 1) / C2T, BN), dim3(C2THR), 0, stream>>>(hw, g5, env);
  k_scan<<<dim3(NBLK), dim3(64), 0, stream>>>(env, ad, sp);  // 4 seqs/wave, 5-lane systolic
  int nmod = MODC * BN * MM;
  k_modA<<<dim3((nmod + 255) / 256), dim3(256), 0, stream>>>(ad, send, mp);
  k_modB<<<dim3((BN * MM + 255) / 256), dim3(256), 0, stream>>>(send, sinit, mp);
  k_modC<<<dim3((nmod + 255) / 256), dim3(256), 0, stream>>>(ad, sinit, out, mp);
}